// Round 10
// baseline (123.027 us; speedup 1.0000x reference)
//
#include <hip/hip_runtime.h>
#include <stdint.h>

#define GN 4008      // reference GRID
#define RPC 8        // rows per chunk
#define CH 501       // x chunks; CH*RPC == GN
#define CPAD 4096    // padded column dim
#define PW 128       // PO u64 words per row
#define TW 512       // y-tile width; 8 tiles per row
#define HPAD 4352    // CPAD + CPAD/16
#define BCAP 256     // per-chunk bucket capacity (mean ~16)
#define NBLK 501     // grid == CH; co-resident by launch_bounds (>=2 blk/CU)
#define NVS 128      // blocks doing the vertical scan (last NVS arrivers)
#define BPB 40       // boxes per block in gather; NBLK*BPB >= 20000

static_assert(CH * RPC == GN, "chunking must cover grid");
static_assert(NBLK * BPB >= 20000, "gather must cover pred");

struct Ctl { double acc; int t1; int t2; int t3; int pad; };

__device__ __forceinline__ int padi(int y) { return y + (y >> 4); }

// Corner q of a box, JAX scatter semantics: negative index wraps (+GN),
// still-OOB (>=GN) dropped. q: 0=(x1,y1,+) 1=(x1,y2+1,-) 2=(x2+1,y1,-) 3=(x2+1,y2+1,+)
__device__ __forceinline__ bool corner1(const float4 b, int q,
                                        int& x, int& y, int& sg) {
    int x1 = (int)rintf(b.x * 100.0f);
    int y1 = (int)rintf(b.y * 100.0f);
    int x2 = (int)rintf(b.z * 100.0f);
    int y2 = (int)rintf(b.w * 100.0f);
    x = (q & 2) ? (x2 + 1) : x1;
    y = (q & 1) ? (y2 + 1) : y1;
    sg = (q == 0 || q == 3) ? 1 : -1;
    if (x < 0) x += GN;
    if (y < 0) y += GN;
    return (x >= 0 && x < GN && y >= 0 && y < GN);
}

__device__ __forceinline__ int clampI(int a) {
    return a < 0 ? 0 : (a > GN ? GN : a);
}

__device__ __forceinline__ int aload(int* p) {
    return __hip_atomic_load(p, __ATOMIC_RELAXED, __HIP_MEMORY_SCOPE_AGENT);
}

// ============ single fused kernel: occ -> (ticket) vscan -> (ticket) gather
__global__ __launch_bounds__(512, 4) void k_all(
    const float* __restrict__ gt, int ngt,
    const float* __restrict__ pred, int npred,
    float* __restrict__ out, Ctl* ctl,
    uint64_t* __restrict__ PO, uint32_t* __restrict__ Crow32,
    int* __restrict__ Ic)
{
    __shared__ int H[HPAD];          // column histogram -> h-scanned seed row
    __shared__ int R8[8 * 560];      // per-wave running col sums + row carries
    __shared__ uint32_t owq[1024];   // occ words: 8 rows x 128
    __shared__ uint32_t bkt[BCAP];
    __shared__ uint32_t ssum[32][16][2];
    __shared__ double red8[8];
    __shared__ int nbkt, sh_rank;
    __shared__ int wsum8[8], wtot[8];
    const int c = blockIdx.x, t = threadIdx.x;
    const int tt = t >> 6, j = t & 63;
    const int r0 = c * RPC, y0 = tt * TW;
    int* R = R8 + tt * 560;          // 544 padded cols + 8 row carries
    int* cD = R + 544;
    for (int i = t; i < HPAD; i += 512) H[i] = 0;
    for (int i = j; i < 560; i += 64) R[i] = 0;
    if (t == 0) nbkt = 0;
    __syncthreads();
    // ---- occ (a): corner scan; x<r0 -> histogram, in-chunk -> bucket ------
    for (int i = t; i < ngt; i += 512) {
        float4 b = ((const float4*)gt)[i];
        #pragma unroll
        for (int q = 0; q < 4; ++q) {
            int x, y, sg;
            if (corner1(b, q, x, y, sg)) {
                if (x < r0) {
                    atomicAdd(&H[padi(y)], sg);
                } else if (x < r0 + RPC) {
                    int pos = atomicAdd(&nbkt, 1);
                    if (pos < BCAP)
                        bkt[pos] = (uint32_t)(((x & 7) << 13) | (y << 1) | (sg > 0 ? 1 : 0));
                }
            }
        }
    }
    __syncthreads();
    // ---- occ (b): block-wide inclusive h-scan of H ------------------------
    const int cb8 = t * 8;
    {
        int hv[8], hs = 0;
        #pragma unroll
        for (int k = 0; k < 8; ++k) { hs += H[padi(cb8 + k)]; hv[k] = hs; }
        int ss = hs;
        #pragma unroll
        for (int d = 1; d < 64; d <<= 1) {
            int tmp = __shfl_up(ss, d);
            if (j >= d) ss += tmp;
        }
        if (j == 63) wsum8[tt] = ss;
        __syncthreads();
        int hc = ss - hs;
        #pragma unroll
        for (int w = 0; w < 8; ++w) if (w < tt) hc += wsum8[w];
        #pragma unroll
        for (int k = 0; k < 8; ++k) H[padi(cb8 + k)] = hv[k] + hc;
    }
    __syncthreads();
    // ---- occ (c): bucket distribute for this wave's tile ------------------
    int cnt = nbkt;
    bool fb = (cnt > BCAP);
    int pxr[4] = {-1, -1, -1, -1}, pry[4] = {0, 0, 0, 0}, psg[4] = {0, 0, 0, 0};
    if (!fb) {
        #pragma unroll
        for (int s = 0; s < 4; ++s) {
            int idx = j + 64 * s;
            if (idx < cnt) {
                uint32_t e = bkt[idx];
                int y = (int)((e >> 1) & 0xFFFu), xr = (int)(e >> 13);
                int sg = (e & 1u) ? 1 : -1;
                int ry = y - y0;
                if (ry >= 0 && ry < TW) { pxr[s] = xr; pry[s] = ry; psg[s] = sg; }
                else if (ry < 0) atomicAdd(&cD[xr], sg);
            }
        }
    } else {            // overflow fallback (correctness only)
        for (int i = j; i < 4 * ngt; i += 64) {
            float4 b = ((const float4*)gt)[i >> 2];
            int x, y, sg;
            if (corner1(b, i & 3, x, y, sg) && (x >> 3) == c) {
                int ry = y - y0;
                if (ry < 0) atomicAdd(&cD[x & 7], sg);
            }
        }
    }
    const int base = j * 8;
    int h[8];
    #pragma unroll
    for (int k = 0; k < 8; ++k) h[k] = H[padi(y0 + base + k)];
    __syncthreads();
    // ---- occ (d): 8-row walk (all state wave-private -> no barriers) ------
    uint32_t cnt8[8] = {0, 0, 0, 0, 0, 0, 0, 0};
    int cb = 0;
    for (int xr = 0; xr < RPC; ++xr) {
        #pragma unroll
        for (int s = 0; s < 4; ++s)
            if (pxr[s] == xr) atomicAdd(&R[padi(pry[s])], psg[s]);
        if (fb) {
            for (int i = j; i < 4 * ngt; i += 64) {
                float4 b = ((const float4*)gt)[i >> 2];
                int x, y, sg;
                if (corner1(b, i & 3, x, y, sg) && x == r0 + xr) {
                    int ry = y - y0;
                    if (ry >= 0 && ry < TW) atomicAdd(&R[padi(ry)], sg);
                }
            }
        }
        cb += cD[xr];
        int v[8], sl = 0;
        #pragma unroll
        for (int k = 0; k < 8; ++k) { sl += R[padi(base + k)]; v[k] = sl; }
        int ss = sl;
        #pragma unroll
        for (int d = 1; d < 64; d <<= 1) {
            int tmp = __shfl_up(ss, d);
            if (j >= d) ss += tmp;
        }
        int excl = ss - sl + cb;
        uint32_t m = 0;
        #pragma unroll
        for (int k = 0; k < 8; ++k) {
            int gy = y0 + base + k;
            if (gy < GN && (h[k] + excl + v[k]) > 0) m |= (1u << k);
        }
        #pragma unroll
        for (int k = 0; k < 8; ++k) cnt8[k] += (m >> k) & 1u;
        uint32_t wq = m << (8 * (j & 3));
        wq |= __shfl_xor(wq, 1);
        wq |= __shfl_xor(wq, 2);
        if ((j & 3) == 0)
            owq[xr * 128 + tt * 16 + (j >> 2)] = wq;
    }
    __syncthreads();                 // owq complete across waves
    // ---- PO: wave tt emits row r0+tt --------------------------------------
    {
        uint32_t w0 = owq[tt * 128 + 2 * j];
        uint32_t w1 = owq[tt * 128 + 2 * j + 1];
        int p0 = __popc(w0), p1 = __popc(w1);
        int tot = p0 + p1;
        int ss = tot;
        #pragma unroll
        for (int d = 1; d < 64; d <<= 1) {
            int tmp = __shfl_up(ss, d);
            if (j >= d) ss += tmp;
        }
        int excl = ss - tot;
        ulonglong2 o;
        o.x = (uint64_t)w0 | ((uint64_t)(uint32_t)excl << 48);
        o.y = (uint64_t)w1 | ((uint64_t)(uint32_t)(excl + p0) << 48);
        ((ulonglong2*)(PO + (size_t)(r0 + tt) * PW))[j] = o;
    }
    // ---- Crow: block-wide h-scan of per-chunk column counts ---------------
    {
        int ctot = 0;
        #pragma unroll
        for (int k = 0; k < 8; ++k) ctot += (int)cnt8[k];
        int ss = ctot;
        #pragma unroll
        for (int d = 1; d < 64; d <<= 1) {
            int tmp = __shfl_up(ss, d);
            if (j >= d) ss += tmp;
        }
        if (j == 63) wtot[tt] = ss;
        __syncthreads();
        int run = ss - ctot;
        #pragma unroll
        for (int w = 0; w < 8; ++w) if (w < tt) run += wtot[w];
        uint32_t pk[4];
        #pragma unroll
        for (int p = 0; p < 4; ++p) {
            run += (int)cnt8[2 * p];
            uint32_t lo = (uint32_t)run & 0xFFFFu;
            run += (int)cnt8[2 * p + 1];
            pk[p] = lo | (((uint32_t)run & 0xFFFFu) << 16);
        }
        *(uint4*)(Crow32 + (((size_t)c * CPAD + y0 + base) >> 1)) =
            make_uint4(pk[0], pk[1], pk[2], pk[3]);
    }
    // ---- handoff 1: release + ticket; last NVS arrivers run the v-scan ----
    __syncthreads();                 // all stores reached L2 (vmcnt drained)
    if (t == 0) {
        __threadfence();             // release PO + Crow (L2 writeback)
        sh_rank = __hip_atomic_fetch_add(&ctl->t1, 1, __ATOMIC_RELAXED,
                                         __HIP_MEMORY_SCOPE_AGENT);
    }
    __syncthreads();
    if (sh_rank >= NBLK - NVS) {
        int slice = sh_rank - (NBLK - NVS);     // 0..127 -> 16 words each
        if (t == 0) {
            while (aload(&ctl->t1) < NBLK) __builtin_amdgcn_s_sleep(64);
            __threadfence();         // acquire all blocks' Crow
        }
        __syncthreads();
        int word = slice * 16 + (t & 15);
        int s = t >> 4;              // 0..31 segments of 16 chunks
        int c0 = s * 16, c1 = min(CH, c0 + 16);
        uint32_t s0 = 0, s1 = 0;
        for (int cc = c0; cc < c1; ++cc) {
            uint32_t v = Crow32[(size_t)cc * (CPAD / 2) + word];
            s0 += v & 0xFFFFu;
            s1 += v >> 16;
        }
        ssum[s][t & 15][0] = s0;
        ssum[s][t & 15][1] = s1;
        __syncthreads();
        uint32_t r0v = 0, r1v = 0;
        for (int k = 0; k < s; ++k) { r0v += ssum[k][t & 15][0]; r1v += ssum[k][t & 15][1]; }
        for (int cc = c0; cc < c1; ++cc) {
            *(int2*)(Ic + (size_t)cc * CPAD + 2 * word) = make_int2((int)r0v, (int)r1v);
            uint32_t v = Crow32[(size_t)cc * (CPAD / 2) + word];
            r0v += v & 0xFFFFu;
            r1v += v >> 16;
        }
        if (c1 == CH)
            *(int2*)(Ic + (size_t)CH * CPAD + 2 * word) = make_int2((int)r0v, (int)r1v);
        __syncthreads();             // Ic stores drained
        if (t == 0) {
            __threadfence();         // release Ic
            __hip_atomic_fetch_add(&ctl->t2, 1, __ATOMIC_RELAXED,
                                   __HIP_MEMORY_SCOPE_AGENT);
        }
    }
    // ---- handoff 2: wait for v-scan, then gather --------------------------
    if (t == 0) {
        while (aload(&ctl->t2) < NVS) __builtin_amdgcn_s_sleep(64);
        __threadfence();             // acquire Ic (+ PO from other blocks)
    }
    __syncthreads();
    double lsum = 0.0;
    const int sub = t & 31, kc = sub >> 3, s8 = sub & 7;
    #pragma unroll
    for (int it = 0; it < 3; ++it) {
        int local = it * 16 + (t >> 5);         // 0..47
        int bi = c * BPB + local;
        bool act = (local < BPB) && (bi < npred);
        int cov = 0;
        int x1 = 0, y1 = 0, x2 = 0, y2 = 0;
        if (act) {
            float4 bx = ((const float4*)pred)[bi];
            x1 = (int)rintf(bx.x * 100.0f);
            y1 = (int)rintf(bx.y * 100.0f);
            x2 = (int)rintf(bx.z * 100.0f);
            y2 = (int)rintf(bx.w * 100.0f);
            int a1 = clampI(x1), b1 = clampI(y1), a2 = clampI(x2), b2 = clampI(y2);
            int a = (kc & 1) ? a1 : a2;
            int b = (kc & 2) ? b1 : b2;
            int sgn = ((kc ^ (kc >> 1)) & 1) ? -1 : 1;
            int Iv = 0;
            if (a > 0 && b > 0) {
                if (s8 == 0) {
                    Iv = Ic[(size_t)(a >> 3) * CPAD + (b - 1)];
                } else {
                    int x = (a & ~7) + s8 - 1;
                    if (x < a) {
                        int bw = b >> 5;
                        uint32_t mask = (1u << (b & 31)) - 1u;   // b&31==0 -> 0
                        uint64_t po = PO[(size_t)x * PW + bw];
                        Iv = (int)(po >> 48) + __popc((uint32_t)po & mask);
                    }
                }
            }
            cov = sgn * Iv;
        }
        cov += __shfl_xor(cov, 1);
        cov += __shfl_xor(cov, 2);
        cov += __shfl_xor(cov, 4);
        cov += __shfl_xor(cov, 8);
        cov += __shfl_xor(cov, 16);
        if (act && sub == 0) {
            int area = (x2 - x1) * (y2 - y1);
            bool valid = (x2 > x1) && (y2 > y1);
            float iou = valid ? ((float)cov / fmaxf((float)area, 1.0f)) : 0.0f;
            lsum += (double)(1.0f - iou);
        }
    }
    #pragma unroll
    for (int d = 32; d > 0; d >>= 1) lsum += __shfl_down(lsum, d);
    if (j == 0) red8[tt] = lsum;
    __syncthreads();
    if (t == 0) {
        double bs = 0.0;
        #pragma unroll
        for (int w = 0; w < 8; ++w) bs += red8[w];
        atomicAdd(&ctl->acc, bs);
        __threadfence();
        if (__hip_atomic_fetch_add(&ctl->t3, 1, __ATOMIC_RELAXED,
                                   __HIP_MEMORY_SCOPE_AGENT) == NBLK - 1) {
            double total = atomicAdd(&ctl->acc, 0.0);   // coherent final read
            out[0] = (float)(total / (double)npred);
        }
    }
}

extern "C" void kernel_launch(void* const* d_in, const int* in_sizes, int n_in,
                              void* d_out, int out_size, void* d_ws, size_t ws_size,
                              hipStream_t stream) {
    const float* pred = (const float*)d_in[0];
    // d_in[1] = target, unused by the reference loss
    const float* gt = (const float*)d_in[2];
    int npred = in_sizes[0] / 4;
    int ngt = in_sizes[2] / 4;

    char* ws = (char*)d_ws;
    size_t off = 0;
    auto alloc = [&](size_t bytes) {
        void* p = ws + off;
        off = (off + bytes + 255) & ~(size_t)255;
        return p;
    };
    Ctl* ctl = (Ctl*)alloc(64);
    int* Ic = (int*)alloc((size_t)(CH + 1) * CPAD * sizeof(int));        // 8.2 MB
    uint64_t* PO = (uint64_t*)alloc((size_t)GN * PW * sizeof(uint64_t)); // 4.1 MB
    uint32_t* Crow = (uint32_t*)alloc((size_t)CH * (CPAD / 2) * sizeof(uint32_t)); // 4.1 MB

    hipMemsetAsync(ctl, 0, 64, stream);
    k_all<<<dim3(NBLK), dim3(512), 0, stream>>>(gt, ngt, pred, npred,
                                                (float*)d_out, ctl, PO, Crow, Ic);
}

// Round 11
// 93.716 us; speedup vs baseline: 1.3128x; 1.3128x over previous
//
#include <hip/hip_runtime.h>
#include <stdint.h>

#define GN 4008      // reference GRID
#define RPC 8        // rows per chunk
#define CH 501       // x chunks; CH*RPC == GN
#define CPAD 4096    // padded column dim
#define PW 128       // PO u64 words per row
#define TW 512       // y-tile width; 8 tiles per row
#define HPAD 4352    // CPAD + CPAD/16
#define BCAP 256     // per-chunk bucket capacity (mean ~16)

static_assert(CH * RPC == GN, "chunking must cover grid");

__device__ __forceinline__ int padi(int y) { return y + (y >> 4); }

// Corner q of a box, JAX scatter semantics: negative index wraps (+GN),
// still-OOB (>=GN) dropped. q: 0=(x1,y1,+) 1=(x1,y2+1,-) 2=(x2+1,y1,-) 3=(x2+1,y2+1,+)
__device__ __forceinline__ bool corner1(const float4 b, int q,
                                        int& x, int& y, int& sg) {
    int x1 = (int)rintf(b.x * 100.0f);
    int y1 = (int)rintf(b.y * 100.0f);
    int x2 = (int)rintf(b.z * 100.0f);
    int y2 = (int)rintf(b.w * 100.0f);
    x = (q & 2) ? (x2 + 1) : x1;
    y = (q & 1) ? (y2 + 1) : y1;
    sg = (q == 0 || q == 3) ? 1 : -1;
    if (x < 0) x += GN;
    if (y < 0) y += GN;
    return (x >= 0 && x < GN && y >= 0 && y < GN);
}

// ---------------- K1: self-contained occ build: gt -> PO + Crow ------------
// (verbatim from round 9 — measured good)
__global__ __launch_bounds__(512, 2) void k_occ(const float* __restrict__ gt, int ngt,
                                                uint64_t* __restrict__ PO,
                                                uint32_t* __restrict__ Crow32,
                                                double* __restrict__ acc,
                                                int* __restrict__ done) {
    __shared__ int H[HPAD];          // column histogram -> h-scanned seed row
    __shared__ int R8[8 * 560];      // per-wave running col sums + row carries
    __shared__ uint32_t owq[1024];   // occ words: 8 rows x 128
    __shared__ uint32_t bkt[BCAP];
    __shared__ int nbkt;
    __shared__ int wsum8[8];
    __shared__ int wtot[8];
    const int c = blockIdx.x, t = threadIdx.x;
    const int tt = t >> 6, j = t & 63;
    const int r0 = c * RPC, y0 = tt * TW;
    int* R = R8 + tt * 560;          // 544 padded cols + 8 row carries
    int* cD = R + 544;
    for (int i = t; i < HPAD; i += 512) H[i] = 0;
    for (int i = j; i < 560; i += 64) R[i] = 0;
    if (t == 0) nbkt = 0;
    if (c == 0 && t == 0) { *acc = 0.0; *done = 0; }
    __syncthreads();
    // (a) corner scan: gt is 32KB, L2-broadcast across blocks
    for (int i = t; i < ngt; i += 512) {
        float4 b = ((const float4*)gt)[i];
        #pragma unroll
        for (int q = 0; q < 4; ++q) {
            int x, y, sg;
            if (corner1(b, q, x, y, sg)) {
                if (x < r0) {
                    atomicAdd(&H[padi(y)], sg);
                } else if (x < r0 + RPC) {
                    int pos = atomicAdd(&nbkt, 1);
                    if (pos < BCAP)
                        bkt[pos] = (uint32_t)(((x & 7) << 13) | (y << 1) | (sg > 0 ? 1 : 0));
                }
            }
        }
    }
    __syncthreads();
    // (b) block-wide inclusive h-scan of H (8 cols per thread)
    const int cb8 = t * 8;
    int hv[8];
    {
        int hs = 0;
        #pragma unroll
        for (int k = 0; k < 8; ++k) { hs += H[padi(cb8 + k)]; hv[k] = hs; }
        int ss = hs;
        #pragma unroll
        for (int d = 1; d < 64; d <<= 1) {
            int tmp = __shfl_up(ss, d);
            if (j >= d) ss += tmp;
        }
        if (j == 63) wsum8[tt] = ss;
        __syncthreads();          // raw-H reads done; wsum8 visible
        int hc = ss - hs;
        #pragma unroll
        for (int w = 0; w < 8; ++w) if (w < tt) hc += wsum8[w];
        #pragma unroll
        for (int k = 0; k < 8; ++k) H[padi(cb8 + k)] = hv[k] + hc;
    }
    __syncthreads();
    // (c) bucket distribute for this wave's tile
    int cnt = nbkt;
    bool fb = (cnt > BCAP);
    int pxr[4] = {-1, -1, -1, -1}, pry[4] = {0, 0, 0, 0}, psg[4] = {0, 0, 0, 0};
    if (!fb) {
        #pragma unroll
        for (int s = 0; s < 4; ++s) {
            int idx = j + 64 * s;
            if (idx < cnt) {
                uint32_t e = bkt[idx];
                int y = (int)((e >> 1) & 0xFFFu), xr = (int)(e >> 13);
                int sg = (e & 1u) ? 1 : -1;
                int ry = y - y0;
                if (ry >= 0 && ry < TW) { pxr[s] = xr; pry[s] = ry; psg[s] = sg; }
                else if (ry < 0) atomicAdd(&cD[xr], sg);
            }
        }
    } else {            // overflow fallback (correctness only)
        for (int i = j; i < 4 * ngt; i += 64) {
            float4 b = ((const float4*)gt)[i >> 2];
            int x, y, sg;
            if (corner1(b, i & 3, x, y, sg) && (x >> 3) == c) {
                int ry = y - y0;
                if (ry < 0) atomicAdd(&cD[x & 7], sg);
            }
        }
    }
    const int base = j * 8;
    int h[8];
    #pragma unroll
    for (int k = 0; k < 8; ++k) h[k] = H[padi(y0 + base + k)];
    __syncthreads();
    // (d) 8-row walk
    uint32_t cnt8[8] = {0, 0, 0, 0, 0, 0, 0, 0};
    int cb = 0;
    for (int xr = 0; xr < RPC; ++xr) {
        #pragma unroll
        for (int s = 0; s < 4; ++s)
            if (pxr[s] == xr) atomicAdd(&R[padi(pry[s])], psg[s]);
        if (fb) {
            for (int i = j; i < 4 * ngt; i += 64) {
                float4 b = ((const float4*)gt)[i >> 2];
                int x, y, sg;
                if (corner1(b, i & 3, x, y, sg) && x == r0 + xr) {
                    int ry = y - y0;
                    if (ry >= 0 && ry < TW) atomicAdd(&R[padi(ry)], sg);
                }
            }
        }
        __syncthreads();
        cb += cD[xr];
        int v[8], sl = 0;
        #pragma unroll
        for (int k = 0; k < 8; ++k) { sl += R[padi(base + k)]; v[k] = sl; }
        int ss = sl;
        #pragma unroll
        for (int d = 1; d < 64; d <<= 1) {
            int tmp = __shfl_up(ss, d);
            if (j >= d) ss += tmp;
        }
        int excl = ss - sl + cb;
        uint32_t m = 0;
        #pragma unroll
        for (int k = 0; k < 8; ++k) {
            int gy = y0 + base + k;
            if (gy < GN && (h[k] + excl + v[k]) > 0) m |= (1u << k);
        }
        #pragma unroll
        for (int k = 0; k < 8; ++k) cnt8[k] += (m >> k) & 1u;
        uint32_t wq = m << (8 * (j & 3));
        wq |= __shfl_xor(wq, 1);
        wq |= __shfl_xor(wq, 2);
        if ((j & 3) == 0)
            owq[xr * 128 + tt * 16 + (j >> 2)] = wq;
        __syncthreads();
    }
    // PO: wave tt emits row r0+tt
    {
        uint32_t w0 = owq[tt * 128 + 2 * j];
        uint32_t w1 = owq[tt * 128 + 2 * j + 1];
        int p0 = __popc(w0), p1 = __popc(w1);
        int tot = p0 + p1;
        int ss = tot;
        #pragma unroll
        for (int d = 1; d < 64; d <<= 1) {
            int tmp = __shfl_up(ss, d);
            if (j >= d) ss += tmp;
        }
        int excl = ss - tot;
        ulonglong2 o;
        o.x = (uint64_t)w0 | ((uint64_t)(uint32_t)excl << 48);
        o.y = (uint64_t)w1 | ((uint64_t)(uint32_t)(excl + p0) << 48);
        ((ulonglong2*)(PO + (size_t)(r0 + tt) * PW))[j] = o;
    }
    // Crow: block-wide h-scan of per-column chunk counts (u16 packed)
    {
        int ctot = 0;
        #pragma unroll
        for (int k = 0; k < 8; ++k) ctot += (int)cnt8[k];
        int ss = ctot;
        #pragma unroll
        for (int d = 1; d < 64; d <<= 1) {
            int tmp = __shfl_up(ss, d);
            if (j >= d) ss += tmp;
        }
        if (j == 63) wtot[tt] = ss;
        __syncthreads();
        int run = ss - ctot;
        #pragma unroll
        for (int w = 0; w < 8; ++w) if (w < tt) run += wtot[w];
        uint32_t pk[4];
        #pragma unroll
        for (int p = 0; p < 4; ++p) {
            run += (int)cnt8[2 * p];
            uint32_t lo = (uint32_t)run & 0xFFFFu;
            run += (int)cnt8[2 * p + 1];
            pk[p] = lo | (((uint32_t)run & 0xFFFFu) << 16);
        }
        *(uint4*)(Crow32 + (((size_t)c * CPAD + y0 + base) >> 1)) =
            make_uint4(pk[0], pk[1], pk[2], pk[3]);
    }
}

// ---------------- K2: vertical exclusive scan of Crow -> Ic ----------------
// (verbatim from round 9 — measured good)
__global__ __launch_bounds__(512) void k_vscanC(const uint32_t* __restrict__ Crow32,
                                                int* __restrict__ Ic) {
    __shared__ uint32_t ssum[32][16][2];
    int w = threadIdx.x & 15, s = threadIdx.x >> 4;
    int word = blockIdx.x * 16 + w;
    int c0 = s * 16, c1 = min(CH, c0 + 16);
    uint32_t s0 = 0, s1 = 0;
    for (int c = c0; c < c1; ++c) {
        uint32_t v = Crow32[(size_t)c * (CPAD / 2) + word];
        s0 += v & 0xFFFFu;
        s1 += v >> 16;
    }
    ssum[s][w][0] = s0;
    ssum[s][w][1] = s1;
    __syncthreads();
    uint32_t r0 = 0, r1 = 0;
    for (int k = 0; k < s; ++k) { r0 += ssum[k][w][0]; r1 += ssum[k][w][1]; }
    for (int c = c0; c < c1; ++c) {
        *(int2*)(Ic + (size_t)c * CPAD + 2 * word) = make_int2((int)r0, (int)r1);
        uint32_t v = Crow32[(size_t)c * (CPAD / 2) + word];
        r0 += v & 0xFFFFu;
        r1 += v >> 16;
    }
    if (c1 == CH)
        *(int2*)(Ic + (size_t)CH * CPAD + 2 * word) = make_int2((int)r0, (int)r1);
}

// ---------------- K3: gather, 32 lanes per box (8 per corner) --------------
// Lane roles per corner: s8==0 -> Ic load; s8=1..7 -> one PO row each.
// Every thread has at most ONE dependent global load (chain depth 4.5 -> 1).
__device__ __forceinline__ int clampI(int a) {
    return a < 0 ? 0 : (a > GN ? GN : a);
}

__global__ __launch_bounds__(256) void k_gather(const float* __restrict__ pred, int npred,
                                                const int* __restrict__ Ic,
                                                const uint64_t* __restrict__ PO,
                                                double* __restrict__ acc,
                                                int* __restrict__ done,
                                                float* __restrict__ out, int nblocks) {
    __shared__ double red[4];
    int g = blockIdx.x * 256 + threadIdx.x;
    int bi = g >> 5;                 // box index
    int sub = g & 31;                // 0..31 within box
    int kc = sub >> 3, s8 = sub & 7; // corner, sub-lane
    double l = 0.0;
    int x1 = 0, y1 = 0, x2 = 0, y2 = 0;
    int cov = 0;
    if (bi < npred) {
        float4 bx = ((const float4*)pred)[bi];
        x1 = (int)rintf(bx.x * 100.0f);
        y1 = (int)rintf(bx.y * 100.0f);
        x2 = (int)rintf(bx.z * 100.0f);
        y2 = (int)rintf(bx.w * 100.0f);
        int a1 = clampI(x1), b1 = clampI(y1), a2 = clampI(x2), b2 = clampI(y2);
        int a = (kc & 1) ? a1 : a2;
        int b = (kc & 2) ? b1 : b2;
        int sgn = ((kc ^ (kc >> 1)) & 1) ? -1 : 1;
        int Iv = 0;
        if (a > 0 && b > 0) {
            if (s8 == 0) {
                Iv = Ic[(size_t)(a >> 3) * CPAD + (b - 1)];
            } else {
                int x = (a & ~7) + s8 - 1;
                if (x < a) {
                    int bw = b >> 5;
                    uint32_t mask = (1u << (b & 31)) - 1u;   // b&31==0 -> 0
                    uint64_t po = PO[(size_t)x * PW + bw];
                    Iv = (int)(po >> 48) + __popc((uint32_t)po & mask);
                }
            }
        }
        cov = sgn * Iv;
    }
    // reduce cov over the 32-lane box group (xor masks < 32 stay in-group)
    cov += __shfl_xor(cov, 1);
    cov += __shfl_xor(cov, 2);
    cov += __shfl_xor(cov, 4);
    cov += __shfl_xor(cov, 8);
    cov += __shfl_xor(cov, 16);
    if (bi < npred && sub == 0) {
        int area = (x2 - x1) * (y2 - y1);
        bool valid = (x2 > x1) && (y2 > y1);
        float iou = valid ? ((float)cov / fmaxf((float)area, 1.0f)) : 0.0f;
        l = (double)(1.0f - iou);
    }
    #pragma unroll
    for (int d = 32; d > 0; d >>= 1) l += __shfl_down(l, d);
    int lane = threadIdx.x & 63, wid = threadIdx.x >> 6;
    if (lane == 0) red[wid] = l;
    __syncthreads();
    if (threadIdx.x == 0) {
        atomicAdd(acc, red[0] + red[1] + red[2] + red[3]);
        __threadfence();
        if (atomicAdd(done, 1) == nblocks - 1) {
            double total = atomicAdd(acc, 0.0);   // coherent read of final sum
            out[0] = (float)(total / (double)npred);
        }
    }
}

extern "C" void kernel_launch(void* const* d_in, const int* in_sizes, int n_in,
                              void* d_out, int out_size, void* d_ws, size_t ws_size,
                              hipStream_t stream) {
    const float* pred = (const float*)d_in[0];
    // d_in[1] = target, unused by the reference loss
    const float* gt = (const float*)d_in[2];
    int npred = in_sizes[0] / 4;
    int ngt = in_sizes[2] / 4;

    char* ws = (char*)d_ws;
    size_t off = 0;
    auto alloc = [&](size_t bytes) {
        void* p = ws + off;
        off = (off + bytes + 255) & ~(size_t)255;
        return p;
    };
    int* Ic = (int*)alloc((size_t)(CH + 1) * CPAD * sizeof(int));        // 8.2 MB
    uint64_t* PO = (uint64_t*)alloc((size_t)GN * PW * sizeof(uint64_t)); // 4.1 MB
    uint32_t* Crow = (uint32_t*)alloc((size_t)CH * (CPAD / 2) * sizeof(uint32_t)); // 4.1 MB
    double* acc = (double*)alloc(sizeof(double));
    int* done = (int*)alloc(sizeof(int));

    int nb = (32 * npred + 255) / 256;
    k_occ<<<dim3(CH), dim3(512), 0, stream>>>(gt, ngt, PO, Crow, acc, done);
    k_vscanC<<<dim3(CPAD / 32), dim3(512), 0, stream>>>(Crow, Ic);
    k_gather<<<dim3(nb), dim3(256), 0, stream>>>(pred, npred, Ic, PO, acc, done,
                                                 (float*)d_out, nb);
}

// Round 12
// 47.268 us; speedup vs baseline: 2.6028x; 1.9826x over previous
//
#include <hip/hip_runtime.h>
#include <stdint.h>

#define GN 4008      // reference GRID
#define RPC 8        // rows per chunk
#define CH 501       // x chunks; CH*RPC == GN
#define CPAD 4096    // padded column dim
#define PW 128       // PO u64 words per row
#define TW 512       // y-tile width; 8 tiles per row
#define HPAD 4352    // CPAD + CPAD/16
#define BCAP 256     // per-chunk bucket capacity (mean ~16)

static_assert(CH * RPC == GN, "chunking must cover grid");

__device__ __forceinline__ int padi(int y) { return y + (y >> 4); }

// Corner q of a box, JAX scatter semantics: negative index wraps (+GN),
// still-OOB (>=GN) dropped. q: 0=(x1,y1,+) 1=(x1,y2+1,-) 2=(x2+1,y1,-) 3=(x2+1,y2+1,+)
__device__ __forceinline__ bool corner1(const float4 b, int q,
                                        int& x, int& y, int& sg) {
    int x1 = (int)rintf(b.x * 100.0f);
    int y1 = (int)rintf(b.y * 100.0f);
    int x2 = (int)rintf(b.z * 100.0f);
    int y2 = (int)rintf(b.w * 100.0f);
    x = (q & 2) ? (x2 + 1) : x1;
    y = (q & 1) ? (y2 + 1) : y1;
    sg = (q == 0 || q == 3) ? 1 : -1;
    if (x < 0) x += GN;
    if (y < 0) y += GN;
    return (x >= 0 && x < GN && y >= 0 && y < GN);
}

// ---------------- K1: self-contained occ build: gt -> PO + Crow ------------
// (verbatim from round 9 — measured good)
__global__ __launch_bounds__(512, 2) void k_occ(const float* __restrict__ gt, int ngt,
                                                uint64_t* __restrict__ PO,
                                                uint32_t* __restrict__ Crow32,
                                                double* __restrict__ acc,
                                                int* __restrict__ done) {
    __shared__ int H[HPAD];          // column histogram -> h-scanned seed row
    __shared__ int R8[8 * 560];      // per-wave running col sums + row carries
    __shared__ uint32_t owq[1024];   // occ words: 8 rows x 128
    __shared__ uint32_t bkt[BCAP];
    __shared__ int nbkt;
    __shared__ int wsum8[8];
    __shared__ int wtot[8];
    const int c = blockIdx.x, t = threadIdx.x;
    const int tt = t >> 6, j = t & 63;
    const int r0 = c * RPC, y0 = tt * TW;
    int* R = R8 + tt * 560;          // 544 padded cols + 8 row carries
    int* cD = R + 544;
    for (int i = t; i < HPAD; i += 512) H[i] = 0;
    for (int i = j; i < 560; i += 64) R[i] = 0;
    if (t == 0) nbkt = 0;
    if (c == 0 && t == 0) { *acc = 0.0; *done = 0; }
    __syncthreads();
    // (a) corner scan: gt is 32KB, L2-broadcast across blocks
    for (int i = t; i < ngt; i += 512) {
        float4 b = ((const float4*)gt)[i];
        #pragma unroll
        for (int q = 0; q < 4; ++q) {
            int x, y, sg;
            if (corner1(b, q, x, y, sg)) {
                if (x < r0) {
                    atomicAdd(&H[padi(y)], sg);
                } else if (x < r0 + RPC) {
                    int pos = atomicAdd(&nbkt, 1);
                    if (pos < BCAP)
                        bkt[pos] = (uint32_t)(((x & 7) << 13) | (y << 1) | (sg > 0 ? 1 : 0));
                }
            }
        }
    }
    __syncthreads();
    // (b) block-wide inclusive h-scan of H (8 cols per thread)
    const int cb8 = t * 8;
    int hv[8];
    {
        int hs = 0;
        #pragma unroll
        for (int k = 0; k < 8; ++k) { hs += H[padi(cb8 + k)]; hv[k] = hs; }
        int ss = hs;
        #pragma unroll
        for (int d = 1; d < 64; d <<= 1) {
            int tmp = __shfl_up(ss, d);
            if (j >= d) ss += tmp;
        }
        if (j == 63) wsum8[tt] = ss;
        __syncthreads();          // raw-H reads done; wsum8 visible
        int hc = ss - hs;
        #pragma unroll
        for (int w = 0; w < 8; ++w) if (w < tt) hc += wsum8[w];
        #pragma unroll
        for (int k = 0; k < 8; ++k) H[padi(cb8 + k)] = hv[k] + hc;
    }
    __syncthreads();
    // (c) bucket distribute for this wave's tile
    int cnt = nbkt;
    bool fb = (cnt > BCAP);
    int pxr[4] = {-1, -1, -1, -1}, pry[4] = {0, 0, 0, 0}, psg[4] = {0, 0, 0, 0};
    if (!fb) {
        #pragma unroll
        for (int s = 0; s < 4; ++s) {
            int idx = j + 64 * s;
            if (idx < cnt) {
                uint32_t e = bkt[idx];
                int y = (int)((e >> 1) & 0xFFFu), xr = (int)(e >> 13);
                int sg = (e & 1u) ? 1 : -1;
                int ry = y - y0;
                if (ry >= 0 && ry < TW) { pxr[s] = xr; pry[s] = ry; psg[s] = sg; }
                else if (ry < 0) atomicAdd(&cD[xr], sg);
            }
        }
    } else {            // overflow fallback (correctness only)
        for (int i = j; i < 4 * ngt; i += 64) {
            float4 b = ((const float4*)gt)[i >> 2];
            int x, y, sg;
            if (corner1(b, i & 3, x, y, sg) && (x >> 3) == c) {
                int ry = y - y0;
                if (ry < 0) atomicAdd(&cD[x & 7], sg);
            }
        }
    }
    const int base = j * 8;
    int h[8];
    #pragma unroll
    for (int k = 0; k < 8; ++k) h[k] = H[padi(y0 + base + k)];
    __syncthreads();
    // (d) 8-row walk
    uint32_t cnt8[8] = {0, 0, 0, 0, 0, 0, 0, 0};
    int cb = 0;
    for (int xr = 0; xr < RPC; ++xr) {
        #pragma unroll
        for (int s = 0; s < 4; ++s)
            if (pxr[s] == xr) atomicAdd(&R[padi(pry[s])], psg[s]);
        if (fb) {
            for (int i = j; i < 4 * ngt; i += 64) {
                float4 b = ((const float4*)gt)[i >> 2];
                int x, y, sg;
                if (corner1(b, i & 3, x, y, sg) && x == r0 + xr) {
                    int ry = y - y0;
                    if (ry >= 0 && ry < TW) atomicAdd(&R[padi(ry)], sg);
                }
            }
        }
        __syncthreads();
        cb += cD[xr];
        int v[8], sl = 0;
        #pragma unroll
        for (int k = 0; k < 8; ++k) { sl += R[padi(base + k)]; v[k] = sl; }
        int ss = sl;
        #pragma unroll
        for (int d = 1; d < 64; d <<= 1) {
            int tmp = __shfl_up(ss, d);
            if (j >= d) ss += tmp;
        }
        int excl = ss - sl + cb;
        uint32_t m = 0;
        #pragma unroll
        for (int k = 0; k < 8; ++k) {
            int gy = y0 + base + k;
            if (gy < GN && (h[k] + excl + v[k]) > 0) m |= (1u << k);
        }
        #pragma unroll
        for (int k = 0; k < 8; ++k) cnt8[k] += (m >> k) & 1u;
        uint32_t wq = m << (8 * (j & 3));
        wq |= __shfl_xor(wq, 1);
        wq |= __shfl_xor(wq, 2);
        if ((j & 3) == 0)
            owq[xr * 128 + tt * 16 + (j >> 2)] = wq;
        __syncthreads();
    }
    // PO: wave tt emits row r0+tt
    {
        uint32_t w0 = owq[tt * 128 + 2 * j];
        uint32_t w1 = owq[tt * 128 + 2 * j + 1];
        int p0 = __popc(w0), p1 = __popc(w1);
        int tot = p0 + p1;
        int ss = tot;
        #pragma unroll
        for (int d = 1; d < 64; d <<= 1) {
            int tmp = __shfl_up(ss, d);
            if (j >= d) ss += tmp;
        }
        int excl = ss - tot;
        ulonglong2 o;
        o.x = (uint64_t)w0 | ((uint64_t)(uint32_t)excl << 48);
        o.y = (uint64_t)w1 | ((uint64_t)(uint32_t)(excl + p0) << 48);
        ((ulonglong2*)(PO + (size_t)(r0 + tt) * PW))[j] = o;
    }
    // Crow: block-wide h-scan of per-column chunk counts (u16 packed)
    {
        int ctot = 0;
        #pragma unroll
        for (int k = 0; k < 8; ++k) ctot += (int)cnt8[k];
        int ss = ctot;
        #pragma unroll
        for (int d = 1; d < 64; d <<= 1) {
            int tmp = __shfl_up(ss, d);
            if (j >= d) ss += tmp;
        }
        if (j == 63) wtot[tt] = ss;
        __syncthreads();
        int run = ss - ctot;
        #pragma unroll
        for (int w = 0; w < 8; ++w) if (w < tt) run += wtot[w];
        uint32_t pk[4];
        #pragma unroll
        for (int p = 0; p < 4; ++p) {
            run += (int)cnt8[2 * p];
            uint32_t lo = (uint32_t)run & 0xFFFFu;
            run += (int)cnt8[2 * p + 1];
            pk[p] = lo | (((uint32_t)run & 0xFFFFu) << 16);
        }
        *(uint4*)(Crow32 + (((size_t)c * CPAD + y0 + base) >> 1)) =
            make_uint4(pk[0], pk[1], pk[2], pk[3]);
    }
}

// ---------------- K2: vertical exclusive scan of Crow -> Ic ----------------
// (verbatim from round 9 — measured good)
__global__ __launch_bounds__(512) void k_vscanC(const uint32_t* __restrict__ Crow32,
                                                int* __restrict__ Ic) {
    __shared__ uint32_t ssum[32][16][2];
    int w = threadIdx.x & 15, s = threadIdx.x >> 4;
    int word = blockIdx.x * 16 + w;
    int c0 = s * 16, c1 = min(CH, c0 + 16);
    uint32_t s0 = 0, s1 = 0;
    for (int c = c0; c < c1; ++c) {
        uint32_t v = Crow32[(size_t)c * (CPAD / 2) + word];
        s0 += v & 0xFFFFu;
        s1 += v >> 16;
    }
    ssum[s][w][0] = s0;
    ssum[s][w][1] = s1;
    __syncthreads();
    uint32_t r0 = 0, r1 = 0;
    for (int k = 0; k < s; ++k) { r0 += ssum[k][w][0]; r1 += ssum[k][w][1]; }
    for (int c = c0; c < c1; ++c) {
        *(int2*)(Ic + (size_t)c * CPAD + 2 * word) = make_int2((int)r0, (int)r1);
        uint32_t v = Crow32[(size_t)c * (CPAD / 2) + word];
        r0 += v & 0xFFFFu;
        r1 += v >> 16;
    }
    if (c1 == CH)
        *(int2*)(Ic + (size_t)CH * CPAD + 2 * word) = make_int2((int)r0, (int)r1);
}

// ---------------- K3: gather, one thread per corner, batched MLP loads -----
// The Ic load + 7 predicated PO-row loads are issued back-to-back (all
// independent), ONE waitcnt, then combined: chain depth ~4.5 trips -> 1.
__device__ __forceinline__ int clampI(int a) {
    return a < 0 ? 0 : (a > GN ? GN : a);
}

__global__ __launch_bounds__(256) void k_gather(const float* __restrict__ pred, int npred,
                                                const int* __restrict__ Ic,
                                                const uint64_t* __restrict__ PO,
                                                double* __restrict__ acc,
                                                int* __restrict__ done,
                                                float* __restrict__ out, int nblocks) {
    __shared__ double red[4];
    int g = blockIdx.x * 256 + threadIdx.x;
    int i = g >> 2, k = g & 3;
    double l = 0.0;
    int x1 = 0, y1 = 0, x2 = 0, y2 = 0;
    int cov = 0;
    if (i < npred) {
        float4 bx = ((const float4*)pred)[i];
        x1 = (int)rintf(bx.x * 100.0f);
        y1 = (int)rintf(bx.y * 100.0f);
        x2 = (int)rintf(bx.z * 100.0f);
        y2 = (int)rintf(bx.w * 100.0f);
        int a1 = clampI(x1), b1 = clampI(y1), a2 = clampI(x2), b2 = clampI(y2);
        int a = (k & 1) ? a1 : a2;
        int b = (k & 2) ? b1 : b2;
        int sgn = ((k ^ (k >> 1)) & 1) ? -1 : 1;
        int Iv = 0;
        if (a > 0 && b > 0) {
            int bw = b >> 5;
            uint32_t mask = (1u << (b & 31)) - 1u;   // b&31==0 -> 0
            int n = a & 7;                            // rows in partial chunk
            const uint64_t* pr = PO + (size_t)(a & ~7) * PW + bw;
            // issue all loads independently; one waitcnt before combine
            int ic = Ic[(size_t)(a >> 3) * CPAD + (b - 1)];
            uint64_t p[7];
            #pragma unroll
            for (int q = 0; q < 7; ++q)
                p[q] = (q < n) ? pr[(size_t)q * PW] : 0ull;
            Iv = ic;
            #pragma unroll
            for (int q = 0; q < 7; ++q)
                Iv += (int)(p[q] >> 48) + __popc((uint32_t)p[q] & mask);
        }
        cov = sgn * Iv;
    }
    cov += __shfl_xor(cov, 1);
    cov += __shfl_xor(cov, 2);
    if (i < npred && k == 0) {
        int area = (x2 - x1) * (y2 - y1);
        bool valid = (x2 > x1) && (y2 > y1);
        float iou = valid ? ((float)cov / fmaxf((float)area, 1.0f)) : 0.0f;
        l = (double)(1.0f - iou);
    }
    #pragma unroll
    for (int d = 32; d > 0; d >>= 1) l += __shfl_down(l, d);
    int lane = threadIdx.x & 63, wid = threadIdx.x >> 6;
    if (lane == 0) red[wid] = l;
    __syncthreads();
    if (threadIdx.x == 0) {
        atomicAdd(acc, red[0] + red[1] + red[2] + red[3]);
        __threadfence();
        if (atomicAdd(done, 1) == nblocks - 1) {
            double total = atomicAdd(acc, 0.0);   // coherent read of final sum
            out[0] = (float)(total / (double)npred);
        }
    }
}

extern "C" void kernel_launch(void* const* d_in, const int* in_sizes, int n_in,
                              void* d_out, int out_size, void* d_ws, size_t ws_size,
                              hipStream_t stream) {
    const float* pred = (const float*)d_in[0];
    // d_in[1] = target, unused by the reference loss
    const float* gt = (const float*)d_in[2];
    int npred = in_sizes[0] / 4;
    int ngt = in_sizes[2] / 4;

    char* ws = (char*)d_ws;
    size_t off = 0;
    auto alloc = [&](size_t bytes) {
        void* p = ws + off;
        off = (off + bytes + 255) & ~(size_t)255;
        return p;
    };
    int* Ic = (int*)alloc((size_t)(CH + 1) * CPAD * sizeof(int));        // 8.2 MB
    uint64_t* PO = (uint64_t*)alloc((size_t)GN * PW * sizeof(uint64_t)); // 4.1 MB
    uint32_t* Crow = (uint32_t*)alloc((size_t)CH * (CPAD / 2) * sizeof(uint32_t)); // 4.1 MB
    double* acc = (double*)alloc(sizeof(double));
    int* done = (int*)alloc(sizeof(int));

    int nb = (4 * npred + 255) / 256;
    k_occ<<<dim3(CH), dim3(512), 0, stream>>>(gt, ngt, PO, Crow, acc, done);
    k_vscanC<<<dim3(CPAD / 32), dim3(512), 0, stream>>>(Crow, Ic);
    k_gather<<<dim3(nb), dim3(256), 0, stream>>>(pred, npred, Ic, PO, acc, done,
                                                 (float*)d_out, nb);
}

// Round 13
// 43.342 us; speedup vs baseline: 2.8385x; 1.0906x over previous
//
#include <hip/hip_runtime.h>
#include <stdint.h>

#define GN 4008      // reference GRID
#define RPC 8        // rows per chunk
#define CH 501       // x chunks; CH*RPC == GN
#define CPAD 4096    // padded column dim
#define PW 128       // PO u64 words per row
#define TW 512       // y-tile width; 8 tiles per row
#define HPAD 4352    // CPAD + CPAD/16
#define BCAP 256     // per-chunk bucket capacity (mean ~16)

static_assert(CH * RPC == GN, "chunking must cover grid");

__device__ __forceinline__ int padi(int y) { return y + (y >> 4); }

// Corner q of a box, JAX scatter semantics: negative index wraps (+GN),
// still-OOB (>=GN) dropped. q: 0=(x1,y1,+) 1=(x1,y2+1,-) 2=(x2+1,y1,-) 3=(x2+1,y2+1,+)
__device__ __forceinline__ bool corner1(const float4 b, int q,
                                        int& x, int& y, int& sg) {
    int x1 = (int)rintf(b.x * 100.0f);
    int y1 = (int)rintf(b.y * 100.0f);
    int x2 = (int)rintf(b.z * 100.0f);
    int y2 = (int)rintf(b.w * 100.0f);
    x = (q & 2) ? (x2 + 1) : x1;
    y = (q & 1) ? (y2 + 1) : y1;
    sg = (q == 0 || q == 3) ? 1 : -1;
    if (x < 0) x += GN;
    if (y < 0) y += GN;
    return (x >= 0 && x < GN && y >= 0 && y < GN);
}

// ---------------- K1: self-contained occ build: gt -> PO + Crow ------------
// Barrier-minimized: only 5 block-wide barriers (B1 init, B2 scatter-done,
// B3 wsum8, B4 owq-complete, B5 wtot). R/cD are wave-private; LDS ops from a
// single wave complete in issue order, so the row walk needs no barriers.
__global__ __launch_bounds__(512, 2) void k_occ(const float* __restrict__ gt, int ngt,
                                                uint64_t* __restrict__ PO,
                                                uint32_t* __restrict__ Crow32,
                                                double* __restrict__ acc,
                                                int* __restrict__ done) {
    __shared__ int H[HPAD];          // column histogram -> h-scanned seed row
    __shared__ int R8[8 * 560];      // per-wave running col sums + row carries
    __shared__ uint32_t owq[1024];   // occ words: 8 rows x 128
    __shared__ uint32_t bkt[BCAP];
    __shared__ int nbkt;
    __shared__ int wsum8[8];
    __shared__ int wtot[8];
    const int c = blockIdx.x, t = threadIdx.x;
    const int tt = t >> 6, j = t & 63;
    const int r0 = c * RPC, y0 = tt * TW;
    int* R = R8 + tt * 560;          // 544 padded cols + 8 row carries
    int* cD = R + 544;
    for (int i = t; i < HPAD; i += 512) H[i] = 0;
    for (int i = j; i < 560; i += 64) R[i] = 0;
    if (t == 0) nbkt = 0;
    if (c == 0 && t == 0) { *acc = 0.0; *done = 0; }
    __syncthreads();                                   // B1
    // (a) corner scan: gt is 32KB, L2-broadcast across blocks
    for (int i = t; i < ngt; i += 512) {
        float4 b = ((const float4*)gt)[i];
        #pragma unroll
        for (int q = 0; q < 4; ++q) {
            int x, y, sg;
            if (corner1(b, q, x, y, sg)) {
                if (x < r0) {
                    atomicAdd(&H[padi(y)], sg);
                } else if (x < r0 + RPC) {
                    int pos = atomicAdd(&nbkt, 1);
                    if (pos < BCAP)
                        bkt[pos] = (uint32_t)(((x & 7) << 13) | (y << 1) | (sg > 0 ? 1 : 0));
                }
            }
        }
    }
    __syncthreads();                                   // B2
    // (b) block-wide inclusive h-scan of H (8 own cols per thread)
    const int cb8 = t * 8;
    {
        int hv[8], hs = 0;
        #pragma unroll
        for (int k = 0; k < 8; ++k) { hs += H[padi(cb8 + k)]; hv[k] = hs; }
        int ss = hs;
        #pragma unroll
        for (int d = 1; d < 64; d <<= 1) {
            int tmp = __shfl_up(ss, d);
            if (j >= d) ss += tmp;
        }
        if (j == 63) wsum8[tt] = ss;
        __syncthreads();                               // B3
        int hc = ss - hs;
        #pragma unroll
        for (int w = 0; w < 8; ++w) if (w < tt) hc += wsum8[w];
        #pragma unroll
        for (int k = 0; k < 8; ++k) H[padi(cb8 + k)] = hv[k] + hc;  // own slots
    }
    // (c) bucket distribute for this wave's tile (cD wave-private; bkt from B2)
    int cnt = nbkt;
    bool fb = (cnt > BCAP);
    int pxr[4] = {-1, -1, -1, -1}, pry[4] = {0, 0, 0, 0}, psg[4] = {0, 0, 0, 0};
    if (!fb) {
        #pragma unroll
        for (int s = 0; s < 4; ++s) {
            int idx = j + 64 * s;
            if (idx < cnt) {
                uint32_t e = bkt[idx];
                int y = (int)((e >> 1) & 0xFFFu), xr = (int)(e >> 13);
                int sg = (e & 1u) ? 1 : -1;
                int ry = y - y0;
                if (ry >= 0 && ry < TW) { pxr[s] = xr; pry[s] = ry; psg[s] = sg; }
                else if (ry < 0) atomicAdd(&cD[xr], sg);
            }
        }
    } else {            // overflow fallback (correctness only)
        for (int i = j; i < 4 * ngt; i += 64) {
            float4 b = ((const float4*)gt)[i >> 2];
            int x, y, sg;
            if (corner1(b, i & 3, x, y, sg) && (x >> 3) == c) {
                int ry = y - y0;
                if (ry < 0) atomicAdd(&cD[x & 7], sg);
            }
        }
    }
    const int base = j * 8;
    int h[8];
    #pragma unroll
    for (int k = 0; k < 8; ++k) h[k] = H[padi(y0 + base + k)];   // own slots
    // (d) 8-row walk — all state wave-private, no barriers
    uint32_t cnt8[8] = {0, 0, 0, 0, 0, 0, 0, 0};
    int cb = 0;
    for (int xr = 0; xr < RPC; ++xr) {
        #pragma unroll
        for (int s = 0; s < 4; ++s)
            if (pxr[s] == xr) atomicAdd(&R[padi(pry[s])], psg[s]);
        if (fb) {
            for (int i = j; i < 4 * ngt; i += 64) {
                float4 b = ((const float4*)gt)[i >> 2];
                int x, y, sg;
                if (corner1(b, i & 3, x, y, sg) && x == r0 + xr) {
                    int ry = y - y0;
                    if (ry >= 0 && ry < TW) atomicAdd(&R[padi(ry)], sg);
                }
            }
        }
        cb += cD[xr];
        int v[8], sl = 0;
        #pragma unroll
        for (int k = 0; k < 8; ++k) { sl += R[padi(base + k)]; v[k] = sl; }
        int ss = sl;
        #pragma unroll
        for (int d = 1; d < 64; d <<= 1) {
            int tmp = __shfl_up(ss, d);
            if (j >= d) ss += tmp;
        }
        int excl = ss - sl + cb;
        uint32_t m = 0;
        #pragma unroll
        for (int k = 0; k < 8; ++k) {
            int gy = y0 + base + k;
            if (gy < GN && (h[k] + excl + v[k]) > 0) m |= (1u << k);
        }
        #pragma unroll
        for (int k = 0; k < 8; ++k) cnt8[k] += (m >> k) & 1u;
        uint32_t wq = m << (8 * (j & 3));
        wq |= __shfl_xor(wq, 1);
        wq |= __shfl_xor(wq, 2);
        if ((j & 3) == 0)
            owq[xr * 128 + tt * 16 + (j >> 2)] = wq;
    }
    __syncthreads();                                   // B4: owq complete
    // PO: wave tt emits row r0+tt (cross-wave owq read)
    {
        uint32_t w0 = owq[tt * 128 + 2 * j];
        uint32_t w1 = owq[tt * 128 + 2 * j + 1];
        int p0 = __popc(w0), p1 = __popc(w1);
        int tot = p0 + p1;
        int ss = tot;
        #pragma unroll
        for (int d = 1; d < 64; d <<= 1) {
            int tmp = __shfl_up(ss, d);
            if (j >= d) ss += tmp;
        }
        int excl = ss - tot;
        ulonglong2 o;
        o.x = (uint64_t)w0 | ((uint64_t)(uint32_t)excl << 48);
        o.y = (uint64_t)w1 | ((uint64_t)(uint32_t)(excl + p0) << 48);
        ((ulonglong2*)(PO + (size_t)(r0 + tt) * PW))[j] = o;
    }
    // Crow: block-wide h-scan of per-column chunk counts (u16 packed)
    {
        int ctot = 0;
        #pragma unroll
        for (int k = 0; k < 8; ++k) ctot += (int)cnt8[k];
        int ss = ctot;
        #pragma unroll
        for (int d = 1; d < 64; d <<= 1) {
            int tmp = __shfl_up(ss, d);
            if (j >= d) ss += tmp;
        }
        if (j == 63) wtot[tt] = ss;
        __syncthreads();                               // B5
        int run = ss - ctot;
        #pragma unroll
        for (int w = 0; w < 8; ++w) if (w < tt) run += wtot[w];
        uint32_t pk[4];
        #pragma unroll
        for (int p = 0; p < 4; ++p) {
            run += (int)cnt8[2 * p];
            uint32_t lo = (uint32_t)run & 0xFFFFu;
            run += (int)cnt8[2 * p + 1];
            pk[p] = lo | (((uint32_t)run & 0xFFFFu) << 16);
        }
        *(uint4*)(Crow32 + (((size_t)c * CPAD + y0 + base) >> 1)) =
            make_uint4(pk[0], pk[1], pk[2], pk[3]);
    }
}

// ---------------- K2: vertical exclusive scan of Crow -> Ic ----------------
// Single-pass: 16 chunk values register-cached (batched MLP loads), prefix
// in registers, exclusive write including the Ic[CH] tail.
__global__ __launch_bounds__(512) void k_vscanC(const uint32_t* __restrict__ Crow32,
                                                int* __restrict__ Ic) {
    __shared__ uint32_t ssum[32][16][2];
    int w = threadIdx.x & 15, s = threadIdx.x >> 4;
    int word = blockIdx.x * 16 + w;
    int c0 = s * 16;
    uint32_t vals[16];
    #pragma unroll
    for (int q = 0; q < 16; ++q) {
        int cc = c0 + q;
        vals[q] = (cc < CH) ? Crow32[(size_t)cc * (CPAD / 2) + word] : 0u;
    }
    uint32_t s0 = 0, s1 = 0;
    #pragma unroll
    for (int q = 0; q < 16; ++q) { s0 += vals[q] & 0xFFFFu; s1 += vals[q] >> 16; }
    ssum[s][w][0] = s0;
    ssum[s][w][1] = s1;
    __syncthreads();
    uint32_t r0 = 0, r1 = 0;
    for (int k = 0; k < s; ++k) { r0 += ssum[k][w][0]; r1 += ssum[k][w][1]; }
    #pragma unroll
    for (int q = 0; q < 16; ++q) {
        int cc = c0 + q;
        if (cc <= CH)
            *(int2*)(Ic + (size_t)cc * CPAD + 2 * word) = make_int2((int)r0, (int)r1);
        r0 += vals[q] & 0xFFFFu;
        r1 += vals[q] >> 16;
    }
}

// ---------------- K3: gather, one thread per corner, batched MLP loads -----
// (verbatim from round 12)
__device__ __forceinline__ int clampI(int a) {
    return a < 0 ? 0 : (a > GN ? GN : a);
}

__global__ __launch_bounds__(256) void k_gather(const float* __restrict__ pred, int npred,
                                                const int* __restrict__ Ic,
                                                const uint64_t* __restrict__ PO,
                                                double* __restrict__ acc,
                                                int* __restrict__ done,
                                                float* __restrict__ out, int nblocks) {
    __shared__ double red[4];
    int g = blockIdx.x * 256 + threadIdx.x;
    int i = g >> 2, k = g & 3;
    double l = 0.0;
    int x1 = 0, y1 = 0, x2 = 0, y2 = 0;
    int cov = 0;
    if (i < npred) {
        float4 bx = ((const float4*)pred)[i];
        x1 = (int)rintf(bx.x * 100.0f);
        y1 = (int)rintf(bx.y * 100.0f);
        x2 = (int)rintf(bx.z * 100.0f);
        y2 = (int)rintf(bx.w * 100.0f);
        int a1 = clampI(x1), b1 = clampI(y1), a2 = clampI(x2), b2 = clampI(y2);
        int a = (k & 1) ? a1 : a2;
        int b = (k & 2) ? b1 : b2;
        int sgn = ((k ^ (k >> 1)) & 1) ? -1 : 1;
        int Iv = 0;
        if (a > 0 && b > 0) {
            int bw = b >> 5;
            uint32_t mask = (1u << (b & 31)) - 1u;   // b&31==0 -> 0
            int n = a & 7;                            // rows in partial chunk
            const uint64_t* pr = PO + (size_t)(a & ~7) * PW + bw;
            int ic = Ic[(size_t)(a >> 3) * CPAD + (b - 1)];
            uint64_t p[7];
            #pragma unroll
            for (int q = 0; q < 7; ++q)
                p[q] = (q < n) ? pr[(size_t)q * PW] : 0ull;
            Iv = ic;
            #pragma unroll
            for (int q = 0; q < 7; ++q)
                Iv += (int)(p[q] >> 48) + __popc((uint32_t)p[q] & mask);
        }
        cov = sgn * Iv;
    }
    cov += __shfl_xor(cov, 1);
    cov += __shfl_xor(cov, 2);
    if (i < npred && k == 0) {
        int area = (x2 - x1) * (y2 - y1);
        bool valid = (x2 > x1) && (y2 > y1);
        float iou = valid ? ((float)cov / fmaxf((float)area, 1.0f)) : 0.0f;
        l = (double)(1.0f - iou);
    }
    #pragma unroll
    for (int d = 32; d > 0; d >>= 1) l += __shfl_down(l, d);
    int lane = threadIdx.x & 63, wid = threadIdx.x >> 6;
    if (lane == 0) red[wid] = l;
    __syncthreads();
    if (threadIdx.x == 0) {
        atomicAdd(acc, red[0] + red[1] + red[2] + red[3]);
        __threadfence();
        if (atomicAdd(done, 1) == nblocks - 1) {
            double total = atomicAdd(acc, 0.0);   // coherent read of final sum
            out[0] = (float)(total / (double)npred);
        }
    }
}

extern "C" void kernel_launch(void* const* d_in, const int* in_sizes, int n_in,
                              void* d_out, int out_size, void* d_ws, size_t ws_size,
                              hipStream_t stream) {
    const float* pred = (const float*)d_in[0];
    // d_in[1] = target, unused by the reference loss
    const float* gt = (const float*)d_in[2];
    int npred = in_sizes[0] / 4;
    int ngt = in_sizes[2] / 4;

    char* ws = (char*)d_ws;
    size_t off = 0;
    auto alloc = [&](size_t bytes) {
        void* p = ws + off;
        off = (off + bytes + 255) & ~(size_t)255;
        return p;
    };
    int* Ic = (int*)alloc((size_t)(CH + 1) * CPAD * sizeof(int));        // 8.2 MB
    uint64_t* PO = (uint64_t*)alloc((size_t)GN * PW * sizeof(uint64_t)); // 4.1 MB
    uint32_t* Crow = (uint32_t*)alloc((size_t)CH * (CPAD / 2) * sizeof(uint32_t)); // 4.1 MB
    double* acc = (double*)alloc(sizeof(double));
    int* done = (int*)alloc(sizeof(int));

    int nb = (4 * npred + 255) / 256;
    k_occ<<<dim3(CH), dim3(512), 0, stream>>>(gt, ngt, PO, Crow, acc, done);
    k_vscanC<<<dim3(CPAD / 32), dim3(512), 0, stream>>>(Crow, Ic);
    k_gather<<<dim3(nb), dim3(256), 0, stream>>>(pred, npred, Ic, PO, acc, done,
                                                 (float*)d_out, nb);
}